// Round 3
// baseline (62.932 us; speedup 1.0000x reference)
//
#include <hip/hip_runtime.h>

#define TPB 64
#define CH4 65536   // float4 granules per 512x512 plane
#define MPL 262144  // floats per mask plane

static __device__ __forceinline__ void fma4(float4& a, float s, const float4& v) {
    a.x = fmaf(s, v.x, a.x);
    a.y = fmaf(s, v.y, a.y);
    a.z = fmaf(s, v.z, a.z);
    a.w = fmaf(s, v.w, a.w);
}
static __device__ __forceinline__ float4 cvt3(float ka, const float4& A,
                                              float kb, const float4& B,
                                              float kc, const float4& C) {
    float4 r;
    r.x = fmaf(ka, A.x, fmaf(kb, B.x, kc * C.x));
    r.y = fmaf(ka, A.y, fmaf(kb, B.y, kc * C.y));
    r.z = fmaf(ka, A.z, fmaf(kb, B.z, kc * C.z));
    r.w = fmaf(ka, A.w, fmaf(kb, B.w, kc * C.w));
    return r;
}

// In-place DCT -> mask -> IDCT of one 8x8 block held as 8 rows x (lo,hi) float4.
static __device__ __forceinline__ void transform_block(
    float4 xlo[8], float4 xhi[8],
    const float* __restrict__ Dd, const float* __restrict__ Di,
    const float* __restrict__ M)
{
    float4 zlo[8], zhi[8];
    #pragma unroll
    for (int k = 0; k < 8; ++k) {
        float4 tlo = make_float4(0.f, 0.f, 0.f, 0.f);
        float4 thi = make_float4(0.f, 0.f, 0.f, 0.f);
        #pragma unroll
        for (int n = 0; n < 8; ++n) {
            const float d = Dd[k * 8 + n];
            fma4(tlo, d, xlo[n]);
            fma4(thi, d, xhi[n]);
        }
        const float t[8] = {tlo.x, tlo.y, tlo.z, tlo.w, thi.x, thi.y, thi.z, thi.w};
        float z[8];
        #pragma unroll
        for (int l = 0; l < 8; ++l) {
            float a = 0.f;
            #pragma unroll
            for (int m = 0; m < 8; ++m) a = fmaf(t[m], Dd[l * 8 + m], a);
            z[l] = a * M[k * 512 + l];
        }
        zlo[k] = make_float4(z[0], z[1], z[2], z[3]);
        zhi[k] = make_float4(z[4], z[5], z[6], z[7]);
    }
    #pragma unroll
    for (int k = 0; k < 8; ++k) {
        float4 tlo = make_float4(0.f, 0.f, 0.f, 0.f);
        float4 thi = make_float4(0.f, 0.f, 0.f, 0.f);
        #pragma unroll
        for (int n = 0; n < 8; ++n) {
            const float d = Di[k * 8 + n];
            fma4(tlo, d, zlo[n]);
            fma4(thi, d, zhi[n]);
        }
        const float t[8] = {tlo.x, tlo.y, tlo.z, tlo.w, thi.x, thi.y, thi.z, thi.w};
        float z[8];
        #pragma unroll
        for (int l = 0; l < 8; ++l) {
            float a = 0.f;
            #pragma unroll
            for (int m = 0; m < 8; ++m) a = fmaf(t[m], Di[l * 8 + m], a);
            z[l] = a;
        }
        xlo[k] = make_float4(z[0], z[1], z[2], z[3]);
        xhi[k] = make_float4(z[4], z[5], z[6], z[7]);
    }
}

__global__ __launch_bounds__(TPB, 2) void jpeg_fused(
    const float* __restrict__ img,
    const float* __restrict__ Dd,
    const float* __restrict__ Di,
    const float* __restrict__ mask,
    float* __restrict__ out)
{
    // Thread-private park slot: one 16-float4 block per thread.
    // Layout [j][tid] -> granule = j*64+tid -> bank-group = tid%8: conflict-free.
    __shared__ float4 park[16][TPB];

    const int tid = threadIdx.x;        // block-column 0..63
    const int b   = blockIdx.x >> 6;    // batch
    const int rb  = blockIdx.x & 63;    // block-row

    const size_t base4 = ((size_t)b * 1536 + (size_t)rb * 8) * 128;
    const float4* R4 = reinterpret_cast<const float4*>(img) + base4;
    const float4* G4 = R4 + CH4;
    const float4* B4 = R4 + 2 * CH4;
    float4* O4 = reinterpret_cast<float4*>(out) + base4;

    const int g0 = 2 * tid, g1 = 2 * tid + 1;

    // ---- Load RGB block, convert to YUV. Y,U in regs; V parked in LDS. ----
    float4 ylo[8], yhi[8], ulo[8], uhi[8];
    #pragma unroll
    for (int r = 0; r < 8; ++r) {
        const float4 Ra = R4[r * 128 + g0], Rb = R4[r * 128 + g1];
        const float4 Ga = G4[r * 128 + g0], Gb = G4[r * 128 + g1];
        const float4 Ba = B4[r * 128 + g0], Bb = B4[r * 128 + g1];
        ylo[r] = cvt3(0.299f, Ra, 0.587f, Ga, 0.114f, Ba);
        yhi[r] = cvt3(0.299f, Rb, 0.587f, Gb, 0.114f, Bb);
        ulo[r] = cvt3(-0.14713f, Ra, -0.28886f, Ga, 0.436f, Ba);
        uhi[r] = cvt3(-0.14713f, Rb, -0.28886f, Gb, 0.436f, Bb);
        park[r][tid]     = cvt3(0.615f, Ra, -0.51499f, Ga, -0.10001f, Ba);
        park[8 + r][tid] = cvt3(0.615f, Rb, -0.51499f, Gb, -0.10001f, Bb);
    }

    // ---- Y transform (mask plane 0) ----
    transform_block(ylo, yhi, Dd, Di, mask);

    // ---- Park swap: pull raw V out, park processed Y. (same-thread, in-order LDS) ----
    float4 vlo[8], vhi[8];
    #pragma unroll
    for (int j = 0; j < 8; ++j) {
        vlo[j] = park[j][tid];
        vhi[j] = park[8 + j][tid];
    }
    #pragma unroll
    for (int j = 0; j < 8; ++j) {
        park[j][tid]     = ylo[j];
        park[8 + j][tid] = yhi[j];
    }

    // ---- U, V transforms (mask planes 1, 2) ----
    transform_block(ulo, uhi, Dd, Di, mask + MPL);
    transform_block(vlo, vhi, Dd, Di, mask + 2 * MPL);

    // ---- Stream Y rows back, mix YUV->RGB, store ----
    #pragma unroll
    for (int r = 0; r < 8; ++r) {
        const float4 Yl = park[r][tid];
        const float4 Yh = park[8 + r][tid];
        // R = y + 1.13983 v ; G = y - 0.39465 u - 0.5806 v ; B = y + 2.03211 u
        float4 Rl, Rh, Gl, Gh, Bl, Bh;
        Rl.x = fmaf(1.13983f, vlo[r].x, Yl.x); Rl.y = fmaf(1.13983f, vlo[r].y, Yl.y);
        Rl.z = fmaf(1.13983f, vlo[r].z, Yl.z); Rl.w = fmaf(1.13983f, vlo[r].w, Yl.w);
        Rh.x = fmaf(1.13983f, vhi[r].x, Yh.x); Rh.y = fmaf(1.13983f, vhi[r].y, Yh.y);
        Rh.z = fmaf(1.13983f, vhi[r].z, Yh.z); Rh.w = fmaf(1.13983f, vhi[r].w, Yh.w);
        Gl = cvt3(1.f, Yl, -0.39465f, ulo[r], -0.5806f, vlo[r]);
        Gh = cvt3(1.f, Yh, -0.39465f, uhi[r], -0.5806f, vhi[r]);
        Bl.x = fmaf(2.03211f, ulo[r].x, Yl.x); Bl.y = fmaf(2.03211f, ulo[r].y, Yl.y);
        Bl.z = fmaf(2.03211f, ulo[r].z, Yl.z); Bl.w = fmaf(2.03211f, ulo[r].w, Yl.w);
        Bh.x = fmaf(2.03211f, uhi[r].x, Yh.x); Bh.y = fmaf(2.03211f, uhi[r].y, Yh.y);
        Bh.z = fmaf(2.03211f, uhi[r].z, Yh.z); Bh.w = fmaf(2.03211f, uhi[r].w, Yh.w);
        O4[r * 128 + g0]           = Rl;  O4[r * 128 + g1]           = Rh;
        O4[CH4 + r * 128 + g0]     = Gl;  O4[CH4 + r * 128 + g1]     = Gh;
        O4[2 * CH4 + r * 128 + g0] = Bl;  O4[2 * CH4 + r * 128 + g1] = Bh;
    }
}

extern "C" void kernel_launch(void* const* d_in, const int* in_sizes, int n_in,
                              void* d_out, int out_size, void* d_ws, size_t ws_size,
                              hipStream_t stream) {
    const float* img  = (const float*)d_in[0];
    const float* Dd   = (const float*)d_in[1];
    const float* Di   = (const float*)d_in[2];
    const float* mask = (const float*)d_in[3];
    float* out = (float*)d_out;

    const int B = in_sizes[0] / (3 * 512 * 512);   // 32
    dim3 grid(B * 64);                              // one 1-wave wg per (batch, block-row)
    dim3 block(TPB);
    hipLaunchKernelGGL(jpeg_fused, grid, block, 0, stream, img, Dd, Di, mask, out);
}